// Round 3
// baseline (1046.432 us; speedup 1.0000x reference)
//
#include <hip/hip_runtime.h>

// ---------------------------------------------------------------------------
// ConvLSTMNet round 3:
//  - lstm: unchanged structure from R2 (register-resident state update, split
//    bf16 MFMA, 1 barrier/step). Output now row-major feat[64][7040].
//  - FC rewritten: R2's broadcast W vector-loads were VMEM-issue bound
//    (~540us). Now: W read lane-coalesced float4 (read exactly once), A tile
//    staged to LDS and read as same-address broadcast b128, 128 FMA per
//    wave-k -> VALU-bound ~20us for layer 2. Split-K via fp32 atomics.
// ---------------------------------------------------------------------------

#define T_STEPS 256
#define PIX 55
#define MT 16          // sequences per block (MFMA M-tile)
#define TILES 110      // 1760 / 16
#define LOG2E 1.4426950408889634f
#define FC_KMAX 176

typedef float f32x4 __attribute__((ext_vector_type(4)));
typedef __bf16 bf16x8 __attribute__((ext_vector_type(8)));

__global__ __launch_bounds__(256) void lstm_kernel(
    const float* __restrict__ x1, const float* __restrict__ x2,
    const float* __restrict__ wx1, const float* __restrict__ wh1,
    const float* __restrict__ bx1, const float* __restrict__ bh1,
    const float* __restrict__ wx2, const float* __restrict__ wh2,
    const float* __restrict__ bx2, const float* __restrict__ bh2,
    float* __restrict__ feat)   // [64][7040]: row sub*32+b, col (cell*64+u)*55+p
{
    int bid  = blockIdx.x;            // 0..439
    int tile = bid % TILES;
    int cc   = bid / TILES;           // 0..3
    int sub  = cc >> 1, cell = cc & 1;
    const float* x  = sub  ? x2  : x1;
    const float* wx = cell ? wx2 : wx1;
    const float* wh = cell ? wh2 : wh1;
    const float* bx = cell ? bx2 : bx1;
    const float* bh = cell ? bh2 : bh1;

    int tid  = threadIdx.x;
    int w    = tid >> 6;              // wave id = unit subtile (16 units)
    int l    = tid & 63;
    int quad = l >> 4;
    int c16  = l & 15;

    __shared__ float xl[MT * 514];                        // [m][t*2+c], pad 514
    __shared__ __align__(16) __bf16 hb[2][2][MT][72];     // [buf][hi/lo][m][u pad72]

    // ---- stage x for this block's 16 sequences (all 256 steps) ----
    {
        int seq0 = tile * MT;
        for (int i = 0; i < 32; ++i) {
            int idx = tid + 256 * i;          // m*512 + t*2 + c
            int m = idx >> 9;
            int tc = idx & 511;
            int t = tc >> 1, c = tc & 1;
            int seq = seq0 + m;
            int b = seq / PIX, p = seq % PIX;
            xl[m * 514 + tc] = x[((b * T_STEPS + t) * 2 + c) * PIX + p];
        }
    }
    // ---- zero h buffer 0 (both hi and lo) ----
    {
        __bf16* hz = &hb[0][0][0][0];
        for (int i = tid; i < 2 * MT * 72; i += 256) hz[i] = (__bf16)0.0f;
    }

    // ---- register-resident wh B-fragments for 4 gates (hi+lo) ----
    bf16x8 Bhi[4][2], Blo[4][2];
    float btot[4], wx0v[4], wx1v[4];
#pragma unroll
    for (int g = 0; g < 4; ++g) {
        int n = 64 * g + 16 * w + c16;
        btot[g] = bx[n] + bh[n];
        wx0v[g] = wx[n];
        wx1v[g] = wx[256 + n];
#pragma unroll
        for (int q = 0; q < 2; ++q) {
#pragma unroll
            for (int j = 0; j < 8; ++j) {
                int k = 32 * q + 8 * quad + j;
                float wv = wh[k * 256 + n];
                __bf16 hi = (__bf16)wv;
                Bhi[g][q][j] = hi;
                Blo[g][q][j] = (__bf16)(wv - (float)hi);
            }
        }
    }

    float cst[4]  = {0.f, 0.f, 0.f, 0.f};
    float hfin[4] = {0.f, 0.f, 0.f, 0.f};

    __syncthreads();

    for (int t = 0; t < T_STEPS; ++t) {
        int rb = t & 1, wb = rb ^ 1;
        int tx = cell ? (T_STEPS - 1 - t) : t;

        bf16x8 Ah[2], Al[2];
#pragma unroll
        for (int q = 0; q < 2; ++q) {
            Ah[q] = *(const bf16x8*)&hb[rb][0][c16][32 * q + 8 * quad];
            Al[q] = *(const bf16x8*)&hb[rb][1][c16][32 * q + 8 * quad];
        }
        float xa[4], xb_[4];
#pragma unroll
        for (int r = 0; r < 4; ++r) {
            float2 v = *(const float2*)&xl[(4 * quad + r) * 514 + tx * 2];
            xa[r] = v.x; xb_[r] = v.y;
        }

        f32x4 acc[4];
#pragma unroll
        for (int g = 0; g < 4; ++g) {
#pragma unroll
            for (int r = 0; r < 4; ++r)
                acc[g][r] = fmaf(xb_[r], wx1v[g], fmaf(xa[r], wx0v[g], btot[g]));
        }
#pragma unroll
        for (int g = 0; g < 4; ++g) {
            acc[g] = __builtin_amdgcn_mfma_f32_16x16x32_bf16(Ah[0], Bhi[g][0], acc[g], 0, 0, 0);
            acc[g] = __builtin_amdgcn_mfma_f32_16x16x32_bf16(Ah[1], Bhi[g][1], acc[g], 0, 0, 0);
            acc[g] = __builtin_amdgcn_mfma_f32_16x16x32_bf16(Al[0], Bhi[g][0], acc[g], 0, 0, 0);
            acc[g] = __builtin_amdgcn_mfma_f32_16x16x32_bf16(Al[1], Bhi[g][1], acc[g], 0, 0, 0);
            acc[g] = __builtin_amdgcn_mfma_f32_16x16x32_bf16(Ah[0], Blo[g][0], acc[g], 0, 0, 0);
            acc[g] = __builtin_amdgcn_mfma_f32_16x16x32_bf16(Ah[1], Blo[g][1], acc[g], 0, 0, 0);
        }

#pragma unroll
        for (int r = 0; r < 4; ++r) {
            float iv = acc[0][r], fv = acc[1][r], ov = acc[2][r], gv = acc[3][r];
            float ei = __builtin_amdgcn_exp2f(-LOG2E * iv);
            float ef = __builtin_amdgcn_exp2f(-LOG2E * fv);
            float eo = __builtin_amdgcn_exp2f(-LOG2E * ov);
            float eg = __builtin_amdgcn_exp2f(-2.0f * LOG2E * gv);
            float sf  = __builtin_amdgcn_rcpf(1.0f + ef);
            float itg = (1.0f - eg) * __builtin_amdgcn_rcpf((1.0f + ei) * (1.0f + eg));
            float c   = fmaf(sf, cst[r], itg);
            cst[r] = c;
            float ec = __builtin_amdgcn_exp2f(-2.0f * LOG2E * c);
            float h  = (1.0f - ec) * __builtin_amdgcn_rcpf((1.0f + eo) * (1.0f + ec));
            hfin[r] = h;
            int m = 4 * quad + r, u = 16 * w + c16;
            __bf16 hi = (__bf16)h;
            hb[wb][0][m][u] = hi;
            hb[wb][1][m][u] = (__bf16)(h - (float)hi);
        }
        __syncthreads();
    }

#pragma unroll
    for (int r = 0; r < 4; ++r) {
        int m = 4 * quad + r;
        int seq = tile * MT + m;
        int b = seq / PIX, p = seq % PIX;
        int u = 16 * w + c16;
        feat[(size_t)(sub * 32 + b) * 7040 + (cell * 64 + u) * PIX + p] = hfin[r];
    }
}

// ---------------------------------------------------------------------------
// FC: out[64][N] += A[64][K] @ W[K][N] (+bias on y==0). Block: all 64 m
// (wave w -> rows 16w..16w+15), 512 n (lane owns 8 n via two float4 W loads).
// A chunk staged in LDS, read as same-address broadcast b128. Split-K atomics.
// ---------------------------------------------------------------------------
__global__ __launch_bounds__(256) void fc_gemm(const float* __restrict__ A,
                                               const float* __restrict__ W,
                                               const float* __restrict__ bias,
                                               float* __restrict__ out,
                                               int K, int N, int kchunk) {
    __shared__ __align__(16) float al[FC_KMAX * 68];   // [kc][m pad68]
    int tid = threadIdx.x;
    int l   = tid & 63;
    int wv  = tid >> 6;
    int k0  = blockIdx.y * kchunk;
    int kcur = min(kchunk, K - k0);
    if (kcur <= 0) return;                              // uniform, pre-barrier

    // ---- stage A[0:64][k0:k0+kcur] -> al[kc][m] (coalesced global reads) ----
    for (int mg = 0; mg < 64; mg += 4) {
        int m = mg + wv;
        const float* ar = A + (size_t)m * K + k0;
        for (int kc = l; kc < kcur; kc += 64)
            al[kc * 68 + m] = ar[kc];
    }
    __syncthreads();

    int n0 = blockIdx.x * 512 + 4 * l;                  // lane n-groups: n0.., n0+256..
    float acc[16][8];
#pragma unroll
    for (int m = 0; m < 16; ++m)
#pragma unroll
        for (int c = 0; c < 8; ++c) acc[m][c] = 0.0f;

    if (blockIdx.y == 0) {
        float bv[8];
#pragma unroll
        for (int c = 0; c < 8; ++c) {
            int n = n0 + (c & 3) + ((c >> 2) << 8);
            bv[c] = (n < N) ? bias[n] : 0.0f;
        }
#pragma unroll
        for (int m = 0; m < 16; ++m)
#pragma unroll
            for (int c = 0; c < 8; ++c) acc[m][c] = bv[c];
    }

    const float* wr = W + (size_t)k0 * N;
#pragma unroll 2
    for (int kc = 0; kc < kcur; ++kc) {
        float wv8[8];
        size_t kb = (size_t)kc * N;
        if (n0 + 3 < N) {
            float4 t = *(const float4*)&wr[kb + n0];
            wv8[0] = t.x; wv8[1] = t.y; wv8[2] = t.z; wv8[3] = t.w;
        } else {
#pragma unroll
            for (int c = 0; c < 4; ++c) { int n = n0 + c; wv8[c] = (n < N) ? wr[kb + n] : 0.0f; }
        }
        if (n0 + 259 < N) {
            float4 t = *(const float4*)&wr[kb + n0 + 256];
            wv8[4] = t.x; wv8[5] = t.y; wv8[6] = t.z; wv8[7] = t.w;
        } else {
#pragma unroll
            for (int c = 0; c < 4; ++c) { int n = n0 + 256 + c; wv8[4 + c] = (n < N) ? wr[kb + n] : 0.0f; }
        }
        const float4* ap = (const float4*)&al[kc * 68 + 16 * wv];   // broadcast
#pragma unroll
        for (int i = 0; i < 4; ++i) {
            float4 a = ap[i];
            float as[4] = {a.x, a.y, a.z, a.w};
#pragma unroll
            for (int r = 0; r < 4; ++r) {
                int m = 4 * i + r;
#pragma unroll
                for (int c = 0; c < 8; ++c)
                    acc[m][c] = fmaf(as[r], wv8[c], acc[m][c]);
            }
        }
    }

#pragma unroll
    for (int i = 0; i < 16; ++i) {
        int m = 16 * wv + i;
        float* orow = out + (size_t)m * N;
#pragma unroll
        for (int c = 0; c < 8; ++c) {
            int n = n0 + (c & 3) + ((c >> 2) << 8);
            if (n < N) atomicAdd(&orow[n], acc[i][c]);
        }
    }
}

__global__ __launch_bounds__(256) void zero2(float* __restrict__ a, int na,
                                             float* __restrict__ b, int nb) {
    int i = blockIdx.x * 256 + threadIdx.x;
    if (i < na) a[i] = 0.0f;
    if (i < nb) b[i] = 0.0f;
}

extern "C" void kernel_launch(void* const* d_in, const int* in_sizes, int n_in,
                              void* d_out, int out_size, void* d_ws, size_t ws_size,
                              hipStream_t stream) {
    const float* x1  = (const float*)d_in[0];
    const float* x2  = (const float*)d_in[1];
    const float* wx1 = (const float*)d_in[2];
    const float* wh1 = (const float*)d_in[3];
    const float* bx1 = (const float*)d_in[4];
    const float* bh1 = (const float*)d_in[5];
    const float* wx2 = (const float*)d_in[6];
    const float* wh2 = (const float*)d_in[7];
    const float* bx2 = (const float*)d_in[8];
    const float* bh2 = (const float*)d_in[9];
    const float* fw2 = (const float*)d_in[10];
    const float* fb2 = (const float*)d_in[11];
    const float* fw3 = (const float*)d_in[12];
    const float* fb3 = (const float*)d_in[13];
    const float* fw4 = (const float*)d_in[14];
    const float* fb4 = (const float*)d_in[15];
    const float* fw5 = (const float*)d_in[16];
    const float* fb5 = (const float*)d_in[17];

    char* ws = (char*)d_ws;
    float* feat = (float*)ws;                                   // [64][7040]
    float* t1   = feat + (size_t)64 * 7040;                     // [64][3400]
    float* t2   = t1   + (size_t)64 * 3400;                     // [64][1000]
    float* t3   = t2   + (size_t)64 * 1000;                     // [64][500]
    float* o    = (float*)d_out;                                // [64][50]

    lstm_kernel<<<dim3(440), dim3(256), 0, stream>>>(
        x1, x2, wx1, wh1, bx1, bh1, wx2, wh2, bx2, bh2, feat);

    // zero t1,t2,t3 (contiguous 64*4900 floats) and d_out
    zero2<<<dim3(1225), dim3(256), 0, stream>>>(t1, 64 * 4900, o, 64 * 50);

    fc_gemm<<<dim3(7, 40), dim3(256), 0, stream>>>(feat, fw2, fb2, t1, 7040, 3400, 176);
    fc_gemm<<<dim3(2, 64), dim3(256), 0, stream>>>(t1,   fw3, fb3, t2, 3400, 1000,  54);
    fc_gemm<<<dim3(1, 50), dim3(256), 0, stream>>>(t2,   fw4, fb4, t3, 1000,  500,  20);
    fc_gemm<<<dim3(1, 25), dim3(256), 0, stream>>>(t3,   fw5, fb5, o,   500,   50,  20);
}

// Round 4
// 929.980 us; speedup vs baseline: 1.1252x; 1.1252x over previous
//
#include <hip/hip_runtime.h>

// ---------------------------------------------------------------------------
// ConvLSTMNet round 4:
//  - lstm: unchanged from R3 (register-resident state update, split-bf16 MFMA,
//    1 barrier/step). 325 us.
//  - FC: R3's 128-float accumulator spilled to scratch (VGPR=128, WRITE 136MB,
//    VALU 7%) -> latency-bound 336us. Now 64 m x 256 n per block, 64 outputs
//    per thread (acc[16][4] = 64 VGPRs, no spill). Per wave-kc: 1 coalesced
//    float4 W load + 4 broadcast ds_read_b128 + 64 FMA -> VALU-bound ~25us.
// ---------------------------------------------------------------------------

#define T_STEPS 256
#define PIX 55
#define MT 16          // sequences per block (MFMA M-tile)
#define TILES 110      // 1760 / 16
#define LOG2E 1.4426950408889634f
#define FC_KMAX 176

typedef float f32x4 __attribute__((ext_vector_type(4)));
typedef __bf16 bf16x8 __attribute__((ext_vector_type(8)));

__global__ __launch_bounds__(256) void lstm_kernel(
    const float* __restrict__ x1, const float* __restrict__ x2,
    const float* __restrict__ wx1, const float* __restrict__ wh1,
    const float* __restrict__ bx1, const float* __restrict__ bh1,
    const float* __restrict__ wx2, const float* __restrict__ wh2,
    const float* __restrict__ bx2, const float* __restrict__ bh2,
    float* __restrict__ feat)   // [64][7040]: row sub*32+b, col (cell*64+u)*55+p
{
    int bid  = blockIdx.x;            // 0..439
    int tile = bid % TILES;
    int cc   = bid / TILES;           // 0..3
    int sub  = cc >> 1, cell = cc & 1;
    const float* x  = sub  ? x2  : x1;
    const float* wx = cell ? wx2 : wx1;
    const float* wh = cell ? wh2 : wh1;
    const float* bx = cell ? bx2 : bx1;
    const float* bh = cell ? bh2 : bh1;

    int tid  = threadIdx.x;
    int w    = tid >> 6;              // wave id = unit subtile (16 units)
    int l    = tid & 63;
    int quad = l >> 4;
    int c16  = l & 15;

    __shared__ float xl[MT * 514];                        // [m][t*2+c], pad 514
    __shared__ __align__(16) __bf16 hb[2][2][MT][72];     // [buf][hi/lo][m][u pad72]

    {
        int seq0 = tile * MT;
        for (int i = 0; i < 32; ++i) {
            int idx = tid + 256 * i;          // m*512 + t*2 + c
            int m = idx >> 9;
            int tc = idx & 511;
            int t = tc >> 1, c = tc & 1;
            int seq = seq0 + m;
            int b = seq / PIX, p = seq % PIX;
            xl[m * 514 + tc] = x[((b * T_STEPS + t) * 2 + c) * PIX + p];
        }
    }
    {
        __bf16* hz = &hb[0][0][0][0];
        for (int i = tid; i < 2 * MT * 72; i += 256) hz[i] = (__bf16)0.0f;
    }

    bf16x8 Bhi[4][2], Blo[4][2];
    float btot[4], wx0v[4], wx1v[4];
#pragma unroll
    for (int g = 0; g < 4; ++g) {
        int n = 64 * g + 16 * w + c16;
        btot[g] = bx[n] + bh[n];
        wx0v[g] = wx[n];
        wx1v[g] = wx[256 + n];
#pragma unroll
        for (int q = 0; q < 2; ++q) {
#pragma unroll
            for (int j = 0; j < 8; ++j) {
                int k = 32 * q + 8 * quad + j;
                float wv = wh[k * 256 + n];
                __bf16 hi = (__bf16)wv;
                Bhi[g][q][j] = hi;
                Blo[g][q][j] = (__bf16)(wv - (float)hi);
            }
        }
    }

    float cst[4]  = {0.f, 0.f, 0.f, 0.f};
    float hfin[4] = {0.f, 0.f, 0.f, 0.f};

    __syncthreads();

    for (int t = 0; t < T_STEPS; ++t) {
        int rb = t & 1, wb = rb ^ 1;
        int tx = cell ? (T_STEPS - 1 - t) : t;

        bf16x8 Ah[2], Al[2];
#pragma unroll
        for (int q = 0; q < 2; ++q) {
            Ah[q] = *(const bf16x8*)&hb[rb][0][c16][32 * q + 8 * quad];
            Al[q] = *(const bf16x8*)&hb[rb][1][c16][32 * q + 8 * quad];
        }
        float xa[4], xb_[4];
#pragma unroll
        for (int r = 0; r < 4; ++r) {
            float2 v = *(const float2*)&xl[(4 * quad + r) * 514 + tx * 2];
            xa[r] = v.x; xb_[r] = v.y;
        }

        f32x4 acc[4];
#pragma unroll
        for (int g = 0; g < 4; ++g) {
#pragma unroll
            for (int r = 0; r < 4; ++r)
                acc[g][r] = fmaf(xb_[r], wx1v[g], fmaf(xa[r], wx0v[g], btot[g]));
        }
#pragma unroll
        for (int g = 0; g < 4; ++g) {
            acc[g] = __builtin_amdgcn_mfma_f32_16x16x32_bf16(Ah[0], Bhi[g][0], acc[g], 0, 0, 0);
            acc[g] = __builtin_amdgcn_mfma_f32_16x16x32_bf16(Ah[1], Bhi[g][1], acc[g], 0, 0, 0);
            acc[g] = __builtin_amdgcn_mfma_f32_16x16x32_bf16(Al[0], Bhi[g][0], acc[g], 0, 0, 0);
            acc[g] = __builtin_amdgcn_mfma_f32_16x16x32_bf16(Al[1], Bhi[g][1], acc[g], 0, 0, 0);
            acc[g] = __builtin_amdgcn_mfma_f32_16x16x32_bf16(Ah[0], Blo[g][0], acc[g], 0, 0, 0);
            acc[g] = __builtin_amdgcn_mfma_f32_16x16x32_bf16(Ah[1], Blo[g][1], acc[g], 0, 0, 0);
        }

#pragma unroll
        for (int r = 0; r < 4; ++r) {
            float iv = acc[0][r], fv = acc[1][r], ov = acc[2][r], gv = acc[3][r];
            float ei = __builtin_amdgcn_exp2f(-LOG2E * iv);
            float ef = __builtin_amdgcn_exp2f(-LOG2E * fv);
            float eo = __builtin_amdgcn_exp2f(-LOG2E * ov);
            float eg = __builtin_amdgcn_exp2f(-2.0f * LOG2E * gv);
            float sf  = __builtin_amdgcn_rcpf(1.0f + ef);
            float itg = (1.0f - eg) * __builtin_amdgcn_rcpf((1.0f + ei) * (1.0f + eg));
            float c   = fmaf(sf, cst[r], itg);
            cst[r] = c;
            float ec = __builtin_amdgcn_exp2f(-2.0f * LOG2E * c);
            float h  = (1.0f - ec) * __builtin_amdgcn_rcpf((1.0f + eo) * (1.0f + ec));
            hfin[r] = h;
            int m = 4 * quad + r, u = 16 * w + c16;
            __bf16 hi = (__bf16)h;
            hb[wb][0][m][u] = hi;
            hb[wb][1][m][u] = (__bf16)(h - (float)hi);
        }
        __syncthreads();
    }

#pragma unroll
    for (int r = 0; r < 4; ++r) {
        int m = 4 * quad + r;
        int seq = tile * MT + m;
        int b = seq / PIX, p = seq % PIX;
        int u = 16 * w + c16;
        feat[(size_t)(sub * 32 + b) * 7040 + (cell * 64 + u) * PIX + p] = hfin[r];
    }
}

// ---------------------------------------------------------------------------
// FC: out[64][N] += A[64][K] @ W[K][N] (+bias on y==0).
// Block: 64 m (wave w -> rows 16w..16w+15) x 256 n (lane owns 4 n, one float4
// W load per kc). acc[16][4] = 64 VGPRs, no spill. A chunk in LDS, read as
// same-address broadcast b128. Split-K over blockIdx.y with fp32 atomics.
// ---------------------------------------------------------------------------
__global__ __launch_bounds__(256) void fc_gemm(const float* __restrict__ A,
                                               const float* __restrict__ W,
                                               const float* __restrict__ bias,
                                               float* __restrict__ out,
                                               int K, int N, int kchunk) {
    __shared__ __align__(16) float al[FC_KMAX * 68];   // [kc][m pad68]
    int tid = threadIdx.x;
    int l   = tid & 63;
    int wv  = tid >> 6;
    int k0  = blockIdx.y * kchunk;
    int kcur = min(kchunk, K - k0);
    if (kcur <= 0) return;                              // uniform, pre-barrier

    // ---- stage A[0:64][k0:k0+kcur] -> al[kc][m] (coalesced global reads) ----
    for (int mg = 0; mg < 64; mg += 4) {
        int m = mg + wv;
        const float* ar = A + (size_t)m * K + k0;
        for (int kc = l; kc < kcur; kc += 64)
            al[kc * 68 + m] = ar[kc];
    }
    __syncthreads();

    int n0 = blockIdx.x * 256 + 4 * l;
    bool nfull = (n0 + 3 < N);
    float acc[16][4];
#pragma unroll
    for (int m = 0; m < 16; ++m)
#pragma unroll
        for (int c = 0; c < 4; ++c) acc[m][c] = 0.0f;

    if (blockIdx.y == 0) {
        float bv[4];
#pragma unroll
        for (int c = 0; c < 4; ++c) bv[c] = (n0 + c < N) ? bias[n0 + c] : 0.0f;
#pragma unroll
        for (int m = 0; m < 16; ++m)
#pragma unroll
            for (int c = 0; c < 4; ++c) acc[m][c] = bv[c];
    }

    const float* wr = W + (size_t)k0 * N;
#pragma unroll 2
    for (int kc = 0; kc < kcur; ++kc) {
        size_t kb = (size_t)kc * N;
        float wv4[4];
        if (nfull) {
            float4 t = *(const float4*)&wr[kb + n0];
            wv4[0] = t.x; wv4[1] = t.y; wv4[2] = t.z; wv4[3] = t.w;
        } else {
#pragma unroll
            for (int c = 0; c < 4; ++c) { int n = n0 + c; wv4[c] = (n < N) ? wr[kb + n] : 0.0f; }
        }
        const float4* ap = (const float4*)&al[kc * 68 + 16 * wv];   // broadcast
#pragma unroll
        for (int i = 0; i < 4; ++i) {
            float4 a = ap[i];
            float as[4] = {a.x, a.y, a.z, a.w};
#pragma unroll
            for (int r = 0; r < 4; ++r) {
#pragma unroll
                for (int c = 0; c < 4; ++c)
                    acc[4 * i + r][c] = fmaf(as[r], wv4[c], acc[4 * i + r][c]);
            }
        }
    }

#pragma unroll
    for (int i = 0; i < 16; ++i) {
        int m = 16 * wv + i;
        float* orow = out + (size_t)m * N;
#pragma unroll
        for (int c = 0; c < 4; ++c) {
            int n = n0 + c;
            if (n < N) atomicAdd(&orow[n], acc[i][c]);
        }
    }
}

__global__ __launch_bounds__(256) void zero2(float* __restrict__ a, int na,
                                             float* __restrict__ b, int nb) {
    int i = blockIdx.x * 256 + threadIdx.x;
    if (i < na) a[i] = 0.0f;
    if (i < nb) b[i] = 0.0f;
}

extern "C" void kernel_launch(void* const* d_in, const int* in_sizes, int n_in,
                              void* d_out, int out_size, void* d_ws, size_t ws_size,
                              hipStream_t stream) {
    const float* x1  = (const float*)d_in[0];
    const float* x2  = (const float*)d_in[1];
    const float* wx1 = (const float*)d_in[2];
    const float* wh1 = (const float*)d_in[3];
    const float* bx1 = (const float*)d_in[4];
    const float* bh1 = (const float*)d_in[5];
    const float* wx2 = (const float*)d_in[6];
    const float* wh2 = (const float*)d_in[7];
    const float* bx2 = (const float*)d_in[8];
    const float* bh2 = (const float*)d_in[9];
    const float* fw2 = (const float*)d_in[10];
    const float* fb2 = (const float*)d_in[11];
    const float* fw3 = (const float*)d_in[12];
    const float* fb3 = (const float*)d_in[13];
    const float* fw4 = (const float*)d_in[14];
    const float* fb4 = (const float*)d_in[15];
    const float* fw5 = (const float*)d_in[16];
    const float* fb5 = (const float*)d_in[17];

    char* ws = (char*)d_ws;
    float* feat = (float*)ws;                                   // [64][7040]
    float* t1   = feat + (size_t)64 * 7040;                     // [64][3400]
    float* t2   = t1   + (size_t)64 * 3400;                     // [64][1000]
    float* t3   = t2   + (size_t)64 * 1000;                     // [64][500]
    float* o    = (float*)d_out;                                // [64][50]

    lstm_kernel<<<dim3(440), dim3(256), 0, stream>>>(
        x1, x2, wx1, wh1, bx1, bh1, wx2, wh2, bx2, bh2, feat);

    // zero t1,t2,t3 (contiguous 64*4900 floats) and d_out
    zero2<<<dim3(1225), dim3(256), 0, stream>>>(t1, 64 * 4900, o, 64 * 50);

    fc_gemm<<<dim3(14, 40), dim3(256), 0, stream>>>(feat, fw2, fb2, t1, 7040, 3400, 176);
    fc_gemm<<<dim3( 4, 64), dim3(256), 0, stream>>>(t1,   fw3, fb3, t2, 3400, 1000,  54);
    fc_gemm<<<dim3( 2, 50), dim3(256), 0, stream>>>(t2,   fw4, fb4, t3, 1000,  500,  20);
    fc_gemm<<<dim3( 1, 25), dim3(256), 0, stream>>>(t3,   fw5, fb5, o,   500,   50,  20);
}